// Round 1
// baseline (140.632 us; speedup 1.0000x reference)
//
#include <hip/hip_runtime.h>

typedef __attribute__((ext_vector_type(8))) short short8;
typedef __attribute__((ext_vector_type(4))) float f32x4;

__device__ __forceinline__ unsigned short f2bf(float f) {
  unsigned int u = __float_as_uint(f);
  u = (u + 0x7FFFu + ((u >> 16) & 1u)) >> 16;  // RNE
  return (unsigned short)u;
}

__device__ __forceinline__ void gl_lds16(const void* g, void* l) {
  __builtin_amdgcn_global_load_lds(
      (const __attribute__((address_space(1))) void*)g,
      (__attribute__((address_space(3))) void*)l, 16, 0, 0);
}

// ---------------------------------------------------------------- cvt f32->bf16
__global__ void cvt_bf16(const float* __restrict__ in, unsigned short* __restrict__ out, int n4) {
  int i = blockIdx.x * 256 + threadIdx.x;
  if (i >= n4) return;
  float4 v = ((const float4*)in)[i];
  ushort4 o;
  o.x = f2bf(v.x); o.y = f2bf(v.y); o.z = f2bf(v.z); o.w = f2bf(v.w);
  ((ushort4*)out)[i] = o;
}

// ---------------------------------------------------------------- W (KxN f32) -> WT (NxK bf16)
__global__ void transposeW(const float* __restrict__ W, unsigned short* __restrict__ WT, int K, int N) {
  int idx = blockIdx.x * 256 + threadIdx.x;
  if (idx >= N * K) return;
  int n = idx / K, k = idx - n * K;
  WT[idx] = f2bf(W[(size_t)k * N + n]);
}

// ---------------------------------------------------------------- mask -> u8 [b'][n][jlo*16+jhi]
// mask: (4,256,128,128) i32. needed bit for (b',n,j): mask[b', j, 2*(n/64), 2*(n%64)]
__global__ void maskprep(const int* __restrict__ mask, unsigned char* __restrict__ out) {
  __shared__ unsigned char bits[64 * 256];  // [c][j]
  const int j = threadIdx.x;                // 0..255
  const int r2g = blockIdx.x, bp = blockIdx.y;
  const int4* row = (const int4*)(mask + ((size_t)(bp * 256 + j) * 128 + r2g * 2) * 128);
#pragma unroll 8
  for (int q = 0; q < 32; ++q) {
    int4 v = row[q];  // cols 4q..4q+3; even cols -> c = 2q, 2q+1
    bits[(2 * q) * 256 + j] = v.x ? 1 : 0;
    bits[(2 * q + 1) * 256 + j] = v.z ? 1 : 0;
  }
  __syncthreads();
  const int t = threadIdx.x;
  const int c = t >> 2, ch = t & 3;
  uint4* dst = (uint4*)(out + ((size_t)bp * 4096 + r2g * 64 + c) * 256 + ch * 64);
#pragma unroll
  for (int q = 0; q < 4; ++q) {
    unsigned int wd[4];
#pragma unroll
    for (int wq = 0; wq < 4; ++wq) {
      unsigned int v = 0;
#pragma unroll
      for (int bb = 0; bb < 4; ++bb) {
        int ob = ch * 64 + q * 16 + wq * 4 + bb;      // output byte pos = jlo*16 + jhi
        int jj = ((ob & 15) << 4) | (ob >> 4);        // j = jhi*16 + jlo
        v |= ((unsigned int)bits[c * 256 + jj]) << (8 * bb);
      }
      wd[wq] = v;
    }
    uint4 vv; vv.x = wd[0]; vv.y = wd[1]; vv.z = wd[2]; vv.w = wd[3];
    dst[q] = vv;
  }
}

// ---------------------------------------------------------------- GEMM  C = A * BT^T
// A: MxK bf16 row-major, BT: NxK bf16 row-major. 128x128 tile, BK=32, 4 waves.
// MODE 0: C bf16 row-major. MODE 1: C bf16 scattered as [m/256][n][m%256] (V^T). MODE 2: C f32 + bias.
template <int MODE>
__global__ void gemm_bt(const unsigned short* __restrict__ A,
                        const unsigned short* __restrict__ BT,
                        void* __restrict__ Cout, const float* __restrict__ bias,
                        int M, int N, int K) {
  __shared__ unsigned short lds_a[128 * 32];
  __shared__ unsigned short lds_b[128 * 32];
  const int tid = threadIdx.x;
  const int w = tid >> 6;
  const int lane = tid & 63;
  const int lo = lane & 15, hi = lane >> 4;
  const int m0 = blockIdx.x * 128, n0 = blockIdx.y * 128;
  const int wr = w >> 1, wc = w & 1;
  f32x4 acc[4][4];
#pragma unroll
  for (int m = 0; m < 4; ++m)
#pragma unroll
    for (int n = 0; n < 4; ++n) acc[m][n] = (f32x4){0.f, 0.f, 0.f, 0.f};

  for (int k0 = 0; k0 < K; k0 += 32) {
    __syncthreads();  // previous iteration's LDS reads complete
#pragma unroll
    for (int c = 0; c < 2; ++c) {
      int o = (tid + c * 256) * 16;
      int row = o >> 6, colb = o & 63;
      gl_lds16((const char*)A + ((size_t)(m0 + row) * K + k0) * 2 + colb,
               (char*)lds_a + (w * 64 + c * 256) * 16);
    }
#pragma unroll
    for (int c = 0; c < 2; ++c) {
      int o = (tid + c * 256) * 16;
      int row = o >> 6, colb = o & 63;
      gl_lds16((const char*)BT + ((size_t)(n0 + row) * K + k0) * 2 + colb,
               (char*)lds_b + (w * 64 + c * 256) * 16);
    }
    __syncthreads();  // drains vmcnt before barrier -> staged data visible
    short8 a[4], b[4];
#pragma unroll
    for (int m = 0; m < 4; ++m)
      a[m] = *(const short8*)&lds_a[(wr * 64 + m * 16 + lo) * 32 + hi * 8];
#pragma unroll
    for (int n = 0; n < 4; ++n)
      b[n] = *(const short8*)&lds_b[(wc * 64 + n * 16 + lo) * 32 + hi * 8];
#pragma unroll
    for (int m = 0; m < 4; ++m)
#pragma unroll
      for (int n = 0; n < 4; ++n)
        acc[m][n] = __builtin_amdgcn_mfma_f32_16x16x32_bf16(a[m], b[n], acc[m][n], 0, 0, 0);
  }

#pragma unroll
  for (int m = 0; m < 4; ++m)
#pragma unroll
    for (int n = 0; n < 4; ++n) {
      int rbase = m0 + wr * 64 + m * 16 + hi * 4;
      int col = n0 + wc * 64 + n * 16 + lo;
#pragma unroll
      for (int r = 0; r < 4; ++r) {
        int rowg = rbase + r;
        float v = acc[m][n][r];
        if (MODE == 0) {
          ((unsigned short*)Cout)[(size_t)rowg * N + col] = f2bf(v);
        } else if (MODE == 1) {
          ((unsigned short*)Cout)[((size_t)(rowg >> 8) * N + col) * 256 + (rowg & 255)] = f2bf(v);
        } else {
          ((float*)Cout)[(size_t)rowg * N + col] = v + bias[col];
        }
      }
    }
}

// ---------------------------------------------------------------- attention
// grid (qt=64, h=8, b=4), 256 threads (4 waves); wave w handles q-rows [w*16, w*16+16).
// Qb: (4,4096,512) bf16; Kb: (4,256,512) bf16; VTb: (4,512,256) bf16; Mu8: [4][4096][256] (j transposed)
__global__ void attn_kernel(const unsigned short* __restrict__ Qb,
                            const unsigned short* __restrict__ Kb,
                            const unsigned short* __restrict__ VTb,
                            const unsigned char* __restrict__ Mu8,
                            unsigned short* __restrict__ AOb) {
  __shared__ unsigned short kt[256 * 64];   // [j][d] rows 128B, XOR-swizzled
  __shared__ unsigned short vt[64 * 256];   // [d][j] rows 512B, XOR-swizzled
  __shared__ unsigned short pt[4 * 16 * 128];  // per-wave P half-tile, rows 256B, swizzled
  const int tid = threadIdx.x, w = tid >> 6, lane = tid & 63;
  const int lo = lane & 15, hi = lane >> 4;
  const int qt = blockIdx.x, h = blockIdx.y, b = blockIdx.z;

#pragma unroll
  for (int c = 0; c < 8; ++c) {  // K tile 32KB: linear LDS dest, inverse-swizzled global src
    int o = (tid + c * 256) * 16;
    int j = o >> 7, colb = (o & 127) ^ ((j & 7) << 4);
    gl_lds16((const char*)Kb + ((size_t)((b * 256 + j) * 512 + h * 64)) * 2 + colb,
             (char*)kt + (w * 64 + c * 256) * 16);
  }
#pragma unroll
  for (int c = 0; c < 8; ++c) {  // V^T tile 32KB
    int o = (tid + c * 256) * 16;
    int d = o >> 9, colb = (o & 511) ^ ((d & 7) << 4);
    gl_lds16((const char*)VTb + ((size_t)((b * 512 + h * 64 + d) * 256)) * 2 + colb,
             (char*)vt + (w * 64 + c * 256) * 16);
  }
  short8 qf[2];
  {
    int qrow = qt * 64 + w * 16 + lo;
#pragma unroll
    for (int kk = 0; kk < 2; ++kk)
      qf[kk] = *(const short8*)&Qb[(size_t)(b * 4096 + qrow) * 512 + h * 64 + kk * 32 + hi * 8];
  }
  __syncthreads();

  // sim = Q K^T : 16 j-tiles x (K=64 -> 2 mfma)
  f32x4 acc[16];
#pragma unroll
  for (int nt = 0; nt < 16; ++nt) acc[nt] = (f32x4){0.f, 0.f, 0.f, 0.f};
#pragma unroll
  for (int nt = 0; nt < 16; ++nt) {
    int j = nt * 16 + lo;
#pragma unroll
    for (int kk = 0; kk < 2; ++kk) {
      short8 bfr = *(const short8*)((const char*)kt + j * 128 +
                                    (((kk * 32 + hi * 8) * 2) ^ ((j & 7) << 4)));
      acc[nt] = __builtin_amdgcn_mfma_f32_16x16x32_bf16(qf[kk], bfr, acc[nt], 0, 0, 0);
    }
  }

  // scale + mask bias + row softmax (rows: hi*4+r; cols: nt*16+lo)
  const unsigned char* mrow = Mu8 + ((size_t)(h & 3) * 4096 + qt * 64 + w * 16) * 256;
  uint4 mv[4];
#pragma unroll
  for (int r = 0; r < 4; ++r)
    mv[r] = *(const uint4*)(mrow + (hi * 4 + r) * 256 + lo * 16);  // 16 bytes: nt=0..15

  float rmax[4] = {-3e38f, -3e38f, -3e38f, -3e38f};
#pragma unroll
  for (int nt = 0; nt < 16; ++nt) {
#pragma unroll
    for (int r = 0; r < 4; ++r) {
      unsigned int word = (nt < 4) ? mv[r].x : (nt < 8) ? mv[r].y : (nt < 12) ? mv[r].z : mv[r].w;
      unsigned int mbyte = (word >> ((nt & 3) * 8)) & 0xFFu;
      float s = acc[nt][r] * 0.125f;
      if (!mbyte) s += -1e9f;
      acc[nt][r] = s;
      rmax[r] = fmaxf(rmax[r], s);
    }
  }
#pragma unroll
  for (int r = 0; r < 4; ++r) {
#pragma unroll
    for (int m2 = 1; m2 < 16; m2 <<= 1)
      rmax[r] = fmaxf(rmax[r], __shfl_xor(rmax[r], m2, 64));
  }
  float rsum[4] = {0.f, 0.f, 0.f, 0.f};
#pragma unroll
  for (int nt = 0; nt < 16; ++nt)
#pragma unroll
    for (int r = 0; r < 4; ++r) {
      float p = __expf(acc[nt][r] - rmax[r]);
      acc[nt][r] = p;
      rsum[r] += p;
    }
#pragma unroll
  for (int r = 0; r < 4; ++r) {
#pragma unroll
    for (int m2 = 1; m2 < 16; m2 <<= 1)
      rsum[r] += __shfl_xor(rsum[r], m2, 64);
    rsum[r] = 1.f / rsum[r];
  }

  // PV in two K-halves through wave-private LDS P tile
  f32x4 aco[4];
#pragma unroll
  for (int n = 0; n < 4; ++n) aco[n] = (f32x4){0.f, 0.f, 0.f, 0.f};
  unsigned short* ptw = pt + w * 16 * 128;
#pragma unroll
  for (int ph = 0; ph < 2; ++ph) {
#pragma unroll
    for (int nt2 = 0; nt2 < 8; ++nt2) {
      int nt = ph * 8 + nt2;
      int jloc = nt2 * 16 + lo;
#pragma unroll
      for (int r = 0; r < 4; ++r) {
        int row = hi * 4 + r;
        *(unsigned short*)((char*)ptw + row * 256 + ((jloc * 2) ^ ((row & 7) << 4))) =
            f2bf(acc[nt][r] * rsum[r]);
      }
    }
    __syncthreads();
#pragma unroll
    for (int ks = 0; ks < 4; ++ks) {
      int jc = ks * 32 + hi * 8;  // local j element within half
      short8 pa = *(const short8*)((const char*)ptw + lo * 256 + ((jc * 2) ^ ((lo & 7) << 4)));
#pragma unroll
      for (int n = 0; n < 4; ++n) {
        int d = n * 16 + lo;
        short8 vb = *(const short8*)((const char*)vt + d * 512 +
                                     (((ph * 128 + jc) * 2) ^ ((d & 7) << 4)));
        aco[n] = __builtin_amdgcn_mfma_f32_16x16x32_bf16(pa, vb, aco[n], 0, 0, 0);
      }
    }
    __syncthreads();
  }

#pragma unroll
  for (int n = 0; n < 4; ++n) {
    int col = h * 64 + n * 16 + lo;
#pragma unroll
    for (int r = 0; r < 4; ++r) {
      int rowg = qt * 64 + w * 16 + hi * 4 + r;
      AOb[(size_t)(b * 4096 + rowg) * 512 + col] = f2bf(aco[n][r]);
    }
  }
}

// ----------------------------------------------------------------
extern "C" void kernel_launch(void* const* d_in, const int* in_sizes, int n_in,
                              void* d_out, int out_size, void* d_ws, size_t ws_size,
                              hipStream_t stream) {
  const float* x = (const float*)d_in[0];     // (4,4096,512)
  const float* ctx = (const float*)d_in[1];   // (4,256,768)
  const int* mask = (const int*)d_in[2];      // (4,256,128,128)
  const float* Wq = (const float*)d_in[3];    // (512,512)
  const float* Wk = (const float*)d_in[4];    // (768,512)
  const float* Wv = (const float*)d_in[5];    // (768,512)
  const float* Wo = (const float*)d_in[6];    // (512,512)
  const float* bo = (const float*)d_in[7];    // (512,)
  float* out = (float*)d_out;                 // (4,4096,512) f32

  char* ws = (char*)d_ws;
  size_t off = 0;
  auto alloc = [&](size_t bytes) {
    char* p = ws + off;
    off += (bytes + 255) & ~(size_t)255;
    return p;
  };
  unsigned short* xb   = (unsigned short*)alloc((size_t)16384 * 512 * 2);
  unsigned short* ctxb = (unsigned short*)alloc((size_t)1024 * 768 * 2);
  unsigned short* WqT  = (unsigned short*)alloc((size_t)512 * 512 * 2);
  unsigned short* WkT  = (unsigned short*)alloc((size_t)512 * 768 * 2);
  unsigned short* WvT  = (unsigned short*)alloc((size_t)512 * 768 * 2);
  unsigned short* WoT  = (unsigned short*)alloc((size_t)512 * 512 * 2);
  unsigned short* Qb   = (unsigned short*)alloc((size_t)16384 * 512 * 2);
  unsigned short* Kb   = (unsigned short*)alloc((size_t)1024 * 512 * 2);
  unsigned short* VTb  = (unsigned short*)alloc((size_t)4 * 512 * 256 * 2);
  unsigned short* AOb  = (unsigned short*)alloc((size_t)16384 * 512 * 2);
  unsigned char*  Mu8  = (unsigned char*)alloc((size_t)4 * 4096 * 256);

  cvt_bf16<<<8192, 256, 0, stream>>>(x, xb, 2097152);       // 16384*512/4
  cvt_bf16<<<768, 256, 0, stream>>>(ctx, ctxb, 196608);     // 1024*768/4
  transposeW<<<(512 * 512 + 255) / 256, 256, 0, stream>>>(Wq, WqT, 512, 512);
  transposeW<<<(768 * 512 + 255) / 256, 256, 0, stream>>>(Wk, WkT, 768, 512);
  transposeW<<<(768 * 512 + 255) / 256, 256, 0, stream>>>(Wv, WvT, 768, 512);
  transposeW<<<(512 * 512 + 255) / 256, 256, 0, stream>>>(Wo, WoT, 512, 512);
  maskprep<<<dim3(64, 4), 256, 0, stream>>>(mask, Mu8);

  gemm_bt<0><<<dim3(8, 4), 256, 0, stream>>>(ctxb, WkT, Kb, nullptr, 1024, 512, 768);
  gemm_bt<1><<<dim3(8, 4), 256, 0, stream>>>(ctxb, WvT, VTb, nullptr, 1024, 512, 768);
  gemm_bt<0><<<dim3(128, 4), 256, 0, stream>>>(xb, WqT, Qb, nullptr, 16384, 512, 512);

  attn_kernel<<<dim3(64, 8, 4), 256, 0, stream>>>(Qb, Kb, VTb, Mu8, AOb);

  gemm_bt<2><<<dim3(128, 4), 256, 0, stream>>>(AOb, WoT, out, bo, 16384, 512, 512);
}

// Round 2
// 134.626 us; speedup vs baseline: 1.0446x; 1.0446x over previous
//
#include <hip/hip_runtime.h>

typedef __attribute__((ext_vector_type(8))) short short8;
typedef __attribute__((ext_vector_type(4))) float f32x4;

__device__ __forceinline__ unsigned short f2bf(float f) {
  unsigned int u = __float_as_uint(f);
  u = (u + 0x7FFFu + ((u >> 16) & 1u)) >> 16;  // RNE
  return (unsigned short)u;
}

__device__ __forceinline__ void gl_lds16(const void* g, void* l) {
  __builtin_amdgcn_global_load_lds(
      (const __attribute__((address_space(1))) void*)g,
      (__attribute__((address_space(3))) void*)l, 16, 0, 0);
}

// ---------------------------------------------------------------- cvt f32->bf16
__global__ void cvt_bf16(const float* __restrict__ in, unsigned short* __restrict__ out, int n4) {
  int i = blockIdx.x * 256 + threadIdx.x;
  if (i >= n4) return;
  float4 v = ((const float4*)in)[i];
  ushort4 o;
  o.x = f2bf(v.x); o.y = f2bf(v.y); o.z = f2bf(v.z); o.w = f2bf(v.w);
  ((ushort4*)out)[i] = o;
}

// ---------------------------------------------------------------- W (KxN f32) -> WT (NxK bf16)
__global__ void transposeW(const float* __restrict__ W, unsigned short* __restrict__ WT, int K, int N) {
  int idx = blockIdx.x * 256 + threadIdx.x;
  if (idx >= N * K) return;
  int n = idx / K, k = idx - n * K;
  WT[idx] = f2bf(W[(size_t)k * N + n]);
}

// ---------------------------------------------------------------- mask -> u8 [b'][n][jlo*16+jhi]
// mask: (4,256,128,128) i32. needed bit for (b',n,j): mask[b', j, 2*(n/64), 2*(n%64)]
__global__ void maskprep(const int* __restrict__ mask, unsigned char* __restrict__ out) {
  __shared__ unsigned char bits[64 * 256];  // [c][j]
  const int j = threadIdx.x;                // 0..255
  const int r2g = blockIdx.x, bp = blockIdx.y;
  const int4* row = (const int4*)(mask + ((size_t)(bp * 256 + j) * 128 + r2g * 2) * 128);
#pragma unroll 8
  for (int q = 0; q < 32; ++q) {
    int4 v = row[q];  // cols 4q..4q+3; even cols -> c = 2q, 2q+1
    bits[(2 * q) * 256 + j] = v.x ? 1 : 0;
    bits[(2 * q + 1) * 256 + j] = v.z ? 1 : 0;
  }
  __syncthreads();
  const int t = threadIdx.x;
  const int c = t >> 2, ch = t & 3;
  uint4* dst = (uint4*)(out + ((size_t)bp * 4096 + r2g * 64 + c) * 256 + ch * 64);
#pragma unroll
  for (int q = 0; q < 4; ++q) {
    unsigned int wd[4];
#pragma unroll
    for (int wq = 0; wq < 4; ++wq) {
      unsigned int v = 0;
#pragma unroll
      for (int bb = 0; bb < 4; ++bb) {
        int ob = ch * 64 + q * 16 + wq * 4 + bb;      // output byte pos = jlo*16 + jhi
        int jj = ((ob & 15) << 4) | (ob >> 4);        // j = jhi*16 + jlo
        v |= ((unsigned int)bits[c * 256 + jj]) << (8 * bb);
      }
      wd[wq] = v;
    }
    uint4 vv; vv.x = wd[0]; vv.y = wd[1]; vv.z = wd[2]; vv.w = wd[3];
    dst[q] = vv;
  }
}

// ---------------------------------------------------------------- GEMM  C = A * BT^T
// A: MxK bf16 row-major, BT: NxK bf16 row-major. 128x128 tile, BK=32, 4 waves.
// MODE 0: C bf16 row-major. MODE 1: C bf16 scattered as [m/256][n][m%256] (V^T). MODE 2: C f32 + bias.
template <int MODE>
__global__ void gemm_bt(const unsigned short* __restrict__ A,
                        const unsigned short* __restrict__ BT,
                        void* __restrict__ Cout, const float* __restrict__ bias,
                        int M, int N, int K) {
  __shared__ unsigned short lds_a[128 * 32];
  __shared__ unsigned short lds_b[128 * 32];
  const int tid = threadIdx.x;
  const int w = tid >> 6;
  const int lane = tid & 63;
  const int lo = lane & 15, hi = lane >> 4;
  const int m0 = blockIdx.x * 128, n0 = blockIdx.y * 128;
  const int wr = w >> 1, wc = w & 1;
  f32x4 acc[4][4];
#pragma unroll
  for (int m = 0; m < 4; ++m)
#pragma unroll
    for (int n = 0; n < 4; ++n) acc[m][n] = (f32x4){0.f, 0.f, 0.f, 0.f};

  for (int k0 = 0; k0 < K; k0 += 32) {
    __syncthreads();  // previous iteration's LDS reads complete
#pragma unroll
    for (int c = 0; c < 2; ++c) {
      int o = (tid + c * 256) * 16;
      int row = o >> 6, colb = o & 63;
      gl_lds16((const char*)A + ((size_t)(m0 + row) * K + k0) * 2 + colb,
               (char*)lds_a + (w * 64 + c * 256) * 16);
    }
#pragma unroll
    for (int c = 0; c < 2; ++c) {
      int o = (tid + c * 256) * 16;
      int row = o >> 6, colb = o & 63;
      gl_lds16((const char*)BT + ((size_t)(n0 + row) * K + k0) * 2 + colb,
               (char*)lds_b + (w * 64 + c * 256) * 16);
    }
    __syncthreads();  // drains vmcnt before barrier -> staged data visible
    short8 a[4], b[4];
#pragma unroll
    for (int m = 0; m < 4; ++m)
      a[m] = *(const short8*)&lds_a[(wr * 64 + m * 16 + lo) * 32 + hi * 8];
#pragma unroll
    for (int n = 0; n < 4; ++n)
      b[n] = *(const short8*)&lds_b[(wc * 64 + n * 16 + lo) * 32 + hi * 8];
#pragma unroll
    for (int m = 0; m < 4; ++m)
#pragma unroll
      for (int n = 0; n < 4; ++n)
        acc[m][n] = __builtin_amdgcn_mfma_f32_16x16x32_bf16(a[m], b[n], acc[m][n], 0, 0, 0);
  }

#pragma unroll
  for (int m = 0; m < 4; ++m)
#pragma unroll
    for (int n = 0; n < 4; ++n) {
      int rbase = m0 + wr * 64 + m * 16 + hi * 4;
      int col = n0 + wc * 64 + n * 16 + lo;
#pragma unroll
      for (int r = 0; r < 4; ++r) {
        int rowg = rbase + r;
        float v = acc[m][n][r];
        if (MODE == 0) {
          ((unsigned short*)Cout)[(size_t)rowg * N + col] = f2bf(v);
        } else if (MODE == 1) {
          ((unsigned short*)Cout)[((size_t)(rowg >> 8) * N + col) * 256 + (rowg & 255)] = f2bf(v);
        } else {
          ((float*)Cout)[(size_t)rowg * N + col] = v + bias[col];
        }
      }
    }
}

// ---------------------------------------------------------------- attention v2
// 1-D grid 2048 (XCD-swizzled), 256 threads (4 waves). Block handles one (b,h,64 q-rows).
// QK^T+softmax: wave w owns q-rows [w*16, w*16+16). PV: wave w owns quadrant
// (qh=w>>1 -> 32 q-rows, dh=w&1 -> 32 d-cols), V^T fragments read direct from global (L2).
// LDS: 32KB shared buffer: K tile [256][64] swizzled, overlaid by P [64][256] swizzled.
__global__ void attn_kernel(const unsigned short* __restrict__ Qb,
                            const unsigned short* __restrict__ Kb,
                            const unsigned short* __restrict__ VTb,
                            const unsigned char* __restrict__ Mu8,
                            unsigned short* __restrict__ AOb) {
  __shared__ unsigned short kt[256 * 64];  // K tile, then P overlay
  const int tid = threadIdx.x, w = tid >> 6, lane = tid & 63;
  const int lo = lane & 15, hi = lane >> 4;
  // XCD swizzle: launched bid -> work id so each XCD keeps 4 consecutive (b,h) slices
  const int bid = blockIdx.x;
  const int wg = (bid & 7) * 256 + (bid >> 3);
  const int qt = wg & 63, h = (wg >> 6) & 7, b = wg >> 9;

#pragma unroll
  for (int c = 0; c < 8; ++c) {  // K tile 32KB: linear LDS dest, inverse-swizzled global src
    int o = (tid + c * 256) * 16;
    int j = o >> 7, colb = (o & 127) ^ ((j & 7) << 4);
    gl_lds16((const char*)Kb + ((size_t)((b * 256 + j) * 512 + h * 64)) * 2 + colb,
             (char*)kt + (w * 64 + c * 256) * 16);
  }
  short8 qf[2];
  {
    int qrow = qt * 64 + w * 16 + lo;
#pragma unroll
    for (int kk = 0; kk < 2; ++kk)
      qf[kk] = *(const short8*)&Qb[(size_t)(b * 4096 + qrow) * 512 + h * 64 + kk * 32 + hi * 8];
  }
  __syncthreads();

  // sim = Q K^T : 16 j-tiles x (K=64 -> 2 mfma). acc row=q(hi*4+r), col=j(nt*16+lo)
  f32x4 acc[16];
#pragma unroll
  for (int nt = 0; nt < 16; ++nt) acc[nt] = (f32x4){0.f, 0.f, 0.f, 0.f};
#pragma unroll
  for (int nt = 0; nt < 16; ++nt) {
    int j = nt * 16 + lo;
#pragma unroll
    for (int kk = 0; kk < 2; ++kk) {
      short8 bfr = *(const short8*)((const char*)kt + j * 128 +
                                    (((kk * 32 + hi * 8) * 2) ^ ((j & 7) << 4)));
      acc[nt] = __builtin_amdgcn_mfma_f32_16x16x32_bf16(qf[kk], bfr, acc[nt], 0, 0, 0);
    }
  }

  // mask bytes for rows hi*4+r (16 bytes: nt=0..15 each)
  const unsigned char* mrow = Mu8 + ((size_t)(h & 3) * 4096 + qt * 64 + w * 16) * 256;
  uint4 mv[4];
#pragma unroll
  for (int r = 0; r < 4; ++r)
    mv[r] = *(const uint4*)(mrow + (hi * 4 + r) * 256 + lo * 16);

  // softmax: max over ALL cols (shift-invariant; masked killed after exp)
  float rmax[4] = {-3e38f, -3e38f, -3e38f, -3e38f};
#pragma unroll
  for (int nt = 0; nt < 16; ++nt)
#pragma unroll
    for (int r = 0; r < 4; ++r) {
      float s = acc[nt][r] * 0.125f;
      acc[nt][r] = s;
      rmax[r] = fmaxf(rmax[r], s);
    }
#pragma unroll
  for (int r = 0; r < 4; ++r) {
#pragma unroll
    for (int m2 = 1; m2 < 16; m2 <<= 1)
      rmax[r] = fmaxf(rmax[r], __shfl_xor(rmax[r], m2, 64));
  }
  float rsum[4] = {0.f, 0.f, 0.f, 0.f};
#pragma unroll
  for (int nt = 0; nt < 16; ++nt)
#pragma unroll
    for (int r = 0; r < 4; ++r) {
      unsigned int word = (nt < 4) ? mv[r].x : (nt < 8) ? mv[r].y : (nt < 12) ? mv[r].z : mv[r].w;
      unsigned int mbyte = (word >> ((nt & 3) * 8)) & 0xFFu;
      float p = __expf(acc[nt][r] - rmax[r]);
      p = mbyte ? p : 0.f;
      acc[nt][r] = p;
      rsum[r] += p;
    }
#pragma unroll
  for (int r = 0; r < 4; ++r) {
#pragma unroll
    for (int m2 = 1; m2 < 16; m2 <<= 1)
      rsum[r] += __shfl_xor(rsum[r], m2, 64);
    rsum[r] = 1.f / rsum[r];
  }

  __syncthreads();  // all QK^T LDS reads done -> safe to overlay P on kt

  // write P [64][256] bf16, rows 512B, byte col ^= ((q&7)<<4)
  {
    unsigned short* pl = kt;
#pragma unroll
    for (int r = 0; r < 4; ++r) {
      int q = w * 16 + hi * 4 + r;
      char* prow = (char*)pl + q * 512;
      int q7s = (q & 7) << 4;
#pragma unroll
      for (int nt = 0; nt < 16; ++nt) {
        *(unsigned short*)(prow + (((nt * 16 + lo) * 2) ^ q7s)) = f2bf(acc[nt][r] * rsum[r]);
      }
    }
  }
  __syncthreads();

  // PV quadrant: q in [qh*32, qh*32+32), d in [dh*32, dh*32+32), j full 256
  const int dh = w & 1, qh = w >> 1;
  f32x4 aco[2][2];
#pragma unroll
  for (int m = 0; m < 2; ++m)
#pragma unroll
    for (int n = 0; n < 2; ++n) aco[m][n] = (f32x4){0.f, 0.f, 0.f, 0.f};
  const size_t vbase = ((size_t)b * 512 + h * 64 + dh * 32) * 256;
#pragma unroll
  for (int ks = 0; ks < 8; ++ks) {
    short8 pa[2];
#pragma unroll
    for (int m = 0; m < 2; ++m) {
      int q = qh * 32 + m * 16 + lo;
      pa[m] = *(const short8*)((const char*)kt + q * 512 +
                               (((ks * 32 + hi * 8) * 2) ^ ((q & 7) << 4)));
    }
#pragma unroll
    for (int n = 0; n < 2; ++n) {
      short8 vb = *(const short8*)&VTb[vbase + (size_t)(n * 16 + lo) * 256 + ks * 32 + hi * 8];
#pragma unroll
      for (int m = 0; m < 2; ++m)
        aco[m][n] = __builtin_amdgcn_mfma_f32_16x16x32_bf16(pa[m], vb, aco[m][n], 0, 0, 0);
    }
  }

#pragma unroll
  for (int m = 0; m < 2; ++m)
#pragma unroll
    for (int n = 0; n < 2; ++n) {
      int col = h * 64 + dh * 32 + n * 16 + lo;
#pragma unroll
      for (int r = 0; r < 4; ++r) {
        int rowg = qt * 64 + qh * 32 + m * 16 + hi * 4 + r;
        AOb[(size_t)(b * 4096 + rowg) * 512 + col] = f2bf(aco[m][n][r]);
      }
    }
}

// ----------------------------------------------------------------
extern "C" void kernel_launch(void* const* d_in, const int* in_sizes, int n_in,
                              void* d_out, int out_size, void* d_ws, size_t ws_size,
                              hipStream_t stream) {
  const float* x = (const float*)d_in[0];     // (4,4096,512)
  const float* ctx = (const float*)d_in[1];   // (4,256,768)
  const int* mask = (const int*)d_in[2];      // (4,256,128,128)
  const float* Wq = (const float*)d_in[3];    // (512,512)
  const float* Wk = (const float*)d_in[4];    // (768,512)
  const float* Wv = (const float*)d_in[5];    // (768,512)
  const float* Wo = (const float*)d_in[6];    // (512,512)
  const float* bo = (const float*)d_in[7];    // (512,)
  float* out = (float*)d_out;                 // (4,4096,512) f32

  char* ws = (char*)d_ws;
  size_t off = 0;
  auto alloc = [&](size_t bytes) {
    char* p = ws + off;
    off += (bytes + 255) & ~(size_t)255;
    return p;
  };
  unsigned short* xb   = (unsigned short*)alloc((size_t)16384 * 512 * 2);
  unsigned short* ctxb = (unsigned short*)alloc((size_t)1024 * 768 * 2);
  unsigned short* WqT  = (unsigned short*)alloc((size_t)512 * 512 * 2);
  unsigned short* WkT  = (unsigned short*)alloc((size_t)512 * 768 * 2);
  unsigned short* WvT  = (unsigned short*)alloc((size_t)512 * 768 * 2);
  unsigned short* WoT  = (unsigned short*)alloc((size_t)512 * 512 * 2);
  unsigned short* Qb   = (unsigned short*)alloc((size_t)16384 * 512 * 2);
  unsigned short* Kb   = (unsigned short*)alloc((size_t)1024 * 512 * 2);
  unsigned short* VTb  = (unsigned short*)alloc((size_t)4 * 512 * 256 * 2);
  unsigned short* AOb  = (unsigned short*)alloc((size_t)16384 * 512 * 2);
  unsigned char*  Mu8  = (unsigned char*)alloc((size_t)4 * 4096 * 256);

  cvt_bf16<<<8192, 256, 0, stream>>>(x, xb, 2097152);       // 16384*512/4
  cvt_bf16<<<768, 256, 0, stream>>>(ctx, ctxb, 196608);     // 1024*768/4
  transposeW<<<(512 * 512 + 255) / 256, 256, 0, stream>>>(Wq, WqT, 512, 512);
  transposeW<<<(768 * 512 + 255) / 256, 256, 0, stream>>>(Wk, WkT, 768, 512);
  transposeW<<<(768 * 512 + 255) / 256, 256, 0, stream>>>(Wv, WvT, 768, 512);
  transposeW<<<(512 * 512 + 255) / 256, 256, 0, stream>>>(Wo, WoT, 512, 512);
  maskprep<<<dim3(64, 4), 256, 0, stream>>>(mask, Mu8);

  gemm_bt<0><<<dim3(8, 4), 256, 0, stream>>>(ctxb, WkT, Kb, nullptr, 1024, 512, 768);
  gemm_bt<1><<<dim3(8, 4), 256, 0, stream>>>(ctxb, WvT, VTb, nullptr, 1024, 512, 768);
  gemm_bt<0><<<dim3(128, 4), 256, 0, stream>>>(xb, WqT, Qb, nullptr, 16384, 512, 512);

  attn_kernel<<<2048, 256, 0, stream>>>(Qb, Kb, VTb, Mu8, AOb);

  gemm_bt<2><<<dim3(128, 4), 256, 0, stream>>>(AOb, WoT, out, bo, 16384, 512, 512);
}

// Round 3
// 102.614 us; speedup vs baseline: 1.3705x; 1.3120x over previous
//
#include <hip/hip_runtime.h>

typedef __attribute__((ext_vector_type(8))) short short8;
typedef __attribute__((ext_vector_type(4))) float f32x4;

__device__ __forceinline__ unsigned short f2bf(float f) {
  unsigned int u = __float_as_uint(f);
  u = (u + 0x7FFFu + ((u >> 16) & 1u)) >> 16;  // RNE
  return (unsigned short)u;
}

__device__ __forceinline__ void gl_lds16(const void* g, void* l) {
  __builtin_amdgcn_global_load_lds(
      (const __attribute__((address_space(1))) void*)g,
      (__attribute__((address_space(3))) void*)l, 16, 0, 0);
}

// ---------------------------------------------------------------- cvt f32->bf16 (x and ctx fused)
__global__ void cvt_both(const float* __restrict__ x, const float* __restrict__ ctx,
                         unsigned short* __restrict__ xb, unsigned short* __restrict__ ctxb) {
  int i = blockIdx.x * 256 + threadIdx.x;
  const float4* src;
  ushort4* dst;
  if (i < 2097152) {            // 16384*512/4
    src = (const float4*)x + i;
    dst = (ushort4*)xb + i;
  } else {
    int j = i - 2097152;
    if (j >= 196608) return;    // 1024*768/4
    src = (const float4*)ctx + j;
    dst = (ushort4*)ctxb + j;
  }
  float4 v = *src;
  ushort4 o;
  o.x = f2bf(v.x); o.y = f2bf(v.y); o.z = f2bf(v.z); o.w = f2bf(v.w);
  *dst = o;
}

// ---------------------------------------------------------------- all 4 weights: (KxN f32) -> (NxK bf16), LDS-tiled
__global__ void transW_all(const float* __restrict__ Wq, const float* __restrict__ Wk,
                           const float* __restrict__ Wv, const float* __restrict__ Wo,
                           unsigned short* __restrict__ WqT, unsigned short* __restrict__ WkT,
                           unsigned short* __restrict__ WvT, unsigned short* __restrict__ WoT) {
  __shared__ unsigned short t[64][65];
  const int bid = blockIdx.x;
  const float* W; unsigned short* WT; int K, rel;
  if (bid < 64)       { W = Wq; WT = WqT; K = 512; rel = bid; }
  else if (bid < 160) { W = Wk; WT = WkT; K = 768; rel = bid - 64; }
  else if (bid < 256) { W = Wv; WT = WvT; K = 768; rel = bid - 160; }
  else                { W = Wo; WT = WoT; K = 512; rel = bid - 256; }
  const int N = 512;
  const int tk = rel >> 3, tn = rel & 7;  // N/64 == 8 for all
  const int k0 = tk * 64, n0 = tn * 64;
  const int tt = threadIdx.x;
#pragma unroll
  for (int e = 0; e < 16; ++e) {
    int idx = e * 256 + tt;
    int r = idx >> 6, c = idx & 63;
    t[r][c] = f2bf(W[(size_t)(k0 + r) * N + n0 + c]);  // coalesced over c
  }
  __syncthreads();
#pragma unroll
  for (int e = 0; e < 16; ++e) {
    int idx = e * 256 + tt;
    int rr = idx & 63, cc = idx >> 6;
    WT[(size_t)(n0 + cc) * K + k0 + rr] = t[rr][cc];   // coalesced over rr
  }
}

// ---------------------------------------------------------------- mask -> u8 [b'][n][jlo*16+jhi]
__global__ void maskprep(const int* __restrict__ mask, unsigned char* __restrict__ out) {
  __shared__ unsigned char bits[64 * 256];  // [c][j]
  const int j = threadIdx.x;                // 0..255
  const int r2g = blockIdx.x, bp = blockIdx.y;
  const int4* row = (const int4*)(mask + ((size_t)(bp * 256 + j) * 128 + r2g * 2) * 128);
#pragma unroll 8
  for (int q = 0; q < 32; ++q) {
    int4 v = row[q];
    bits[(2 * q) * 256 + j] = v.x ? 1 : 0;
    bits[(2 * q + 1) * 256 + j] = v.z ? 1 : 0;
  }
  __syncthreads();
  const int t = threadIdx.x;
  const int c = t >> 2, ch = t & 3;
  uint4* dst = (uint4*)(out + ((size_t)bp * 4096 + r2g * 64 + c) * 256 + ch * 64);
#pragma unroll
  for (int q = 0; q < 4; ++q) {
    unsigned int wd[4];
#pragma unroll
    for (int wq = 0; wq < 4; ++wq) {
      unsigned int v = 0;
#pragma unroll
      for (int bb = 0; bb < 4; ++bb) {
        int ob = ch * 64 + q * 16 + wq * 4 + bb;
        int jj = ((ob & 15) << 4) | (ob >> 4);
        v |= ((unsigned int)bits[c * 256 + jj]) << (8 * bb);
      }
      wd[wq] = v;
    }
    uint4 vv; vv.x = wd[0]; vv.y = wd[1]; vv.z = wd[2]; vv.w = wd[3];
    dst[q] = vv;
  }
}

// ---------------------------------------------------------------- 128x128 GEMM, BK=64 (m97 structure)
// A: MxK bf16 rm, BT: NxK bf16 rm. MODE 0: C bf16 rm. MODE 2: C f32 + bias.
template <int MODE>
__global__ void gemm128(const unsigned short* __restrict__ A,
                        const unsigned short* __restrict__ BT,
                        void* __restrict__ Cout, const float* __restrict__ bias,
                        int M, int N, int K) {
  __shared__ unsigned short lds_a[128 * 64];
  __shared__ unsigned short lds_b[128 * 64];
  const int tid = threadIdx.x;
  const int w = tid >> 6, lane = tid & 63;
  const int lo = lane & 15, hi = lane >> 4;
  const int m0 = blockIdx.x * 128, n0 = blockIdx.y * 128;
  const int wr = w >> 1, wc = w & 1;
  f32x4 acc[4][4];
#pragma unroll
  for (int m = 0; m < 4; ++m)
#pragma unroll
    for (int n = 0; n < 4; ++n) acc[m][n] = (f32x4){0.f, 0.f, 0.f, 0.f};

  for (int k0 = 0; k0 < K; k0 += 64) {
    __syncthreads();
#pragma unroll
    for (int c = 0; c < 4; ++c) {
      int o = (tid + c * 256) * 16;
      int row = o >> 7, colb = o & 127;
      gl_lds16((const char*)A + ((size_t)(m0 + row) * K + k0) * 2 + colb,
               (char*)lds_a + (w * 64 + c * 256) * 16);
    }
#pragma unroll
    for (int c = 0; c < 4; ++c) {
      int o = (tid + c * 256) * 16;
      int row = o >> 7, colb = o & 127;
      gl_lds16((const char*)BT + ((size_t)(n0 + row) * K + k0) * 2 + colb,
               (char*)lds_b + (w * 64 + c * 256) * 16);
    }
    __syncthreads();
    short8 a[2][4], b[2][4];
#pragma unroll
    for (int kk = 0; kk < 2; ++kk) {
#pragma unroll
      for (int m = 0; m < 4; ++m)
        a[kk][m] = *(const short8*)&lds_a[(wr * 64 + m * 16 + lo) * 64 + kk * 32 + hi * 8];
#pragma unroll
      for (int n = 0; n < 4; ++n)
        b[kk][n] = *(const short8*)&lds_b[(wc * 64 + n * 16 + lo) * 64 + kk * 32 + hi * 8];
    }
#pragma unroll
    for (int kk = 0; kk < 2; ++kk)
#pragma unroll
      for (int m = 0; m < 4; ++m)
#pragma unroll
        for (int n = 0; n < 4; ++n)
          acc[m][n] = __builtin_amdgcn_mfma_f32_16x16x32_bf16(a[kk][m], b[kk][n], acc[m][n], 0, 0, 0);
  }

#pragma unroll
  for (int m = 0; m < 4; ++m)
#pragma unroll
    for (int n = 0; n < 4; ++n) {
      int rbase = m0 + wr * 64 + m * 16 + hi * 4;
      int col = n0 + wc * 64 + n * 16 + lo;
#pragma unroll
      for (int r = 0; r < 4; ++r) {
        int rowg = rbase + r;
        float v = acc[m][n][r];
        if (MODE == 0) {
          ((unsigned short*)Cout)[(size_t)rowg * N + col] = f2bf(v);
        } else {
          ((float*)Cout)[(size_t)rowg * N + col] = v + bias[col];
        }
      }
    }
}

// ---------------------------------------------------------------- fused K/V projection, 64x64 tiles, BK=64
// A: 1024x768 bf16. z=0: Kb row-major 1024x512. z=1: VTb scatter [m>>8][n][m&255].
__global__ void gemm_kv64(const unsigned short* __restrict__ A,
                          const unsigned short* __restrict__ WkT,
                          const unsigned short* __restrict__ WvT,
                          unsigned short* __restrict__ Kb, unsigned short* __restrict__ VTb) {
  __shared__ unsigned short la[64 * 64];
  __shared__ unsigned short lb[64 * 64];
  const int z = blockIdx.z;
  const unsigned short* BT = z ? WvT : WkT;
  const int tid = threadIdx.x;
  const int w = tid >> 6, lane = tid & 63;
  const int lo = lane & 15, hi = lane >> 4;
  const int m0 = blockIdx.x * 64, n0 = blockIdx.y * 64;
  const int wr = w >> 1, wc = w & 1;
  const int K = 768;
  f32x4 acc[2][2];
#pragma unroll
  for (int m = 0; m < 2; ++m)
#pragma unroll
    for (int n = 0; n < 2; ++n) acc[m][n] = (f32x4){0.f, 0.f, 0.f, 0.f};

  for (int k0 = 0; k0 < K; k0 += 64) {
    __syncthreads();
#pragma unroll
    for (int c = 0; c < 2; ++c) {
      int o = (tid + c * 256) * 16;
      int row = o >> 7, colb = o & 127;
      gl_lds16((const char*)A + ((size_t)(m0 + row) * K + k0) * 2 + colb,
               (char*)la + (w * 64 + c * 256) * 16);
      gl_lds16((const char*)BT + ((size_t)(n0 + row) * K + k0) * 2 + colb,
               (char*)lb + (w * 64 + c * 256) * 16);
    }
    __syncthreads();
    short8 a[2][2], b[2][2];
#pragma unroll
    for (int kk = 0; kk < 2; ++kk) {
#pragma unroll
      for (int m = 0; m < 2; ++m)
        a[kk][m] = *(const short8*)&la[(wr * 32 + m * 16 + lo) * 64 + kk * 32 + hi * 8];
#pragma unroll
      for (int n = 0; n < 2; ++n)
        b[kk][n] = *(const short8*)&lb[(wc * 32 + n * 16 + lo) * 64 + kk * 32 + hi * 8];
    }
#pragma unroll
    for (int kk = 0; kk < 2; ++kk)
#pragma unroll
      for (int m = 0; m < 2; ++m)
#pragma unroll
        for (int n = 0; n < 2; ++n)
          acc[m][n] = __builtin_amdgcn_mfma_f32_16x16x32_bf16(a[kk][m], b[kk][n], acc[m][n], 0, 0, 0);
  }

#pragma unroll
  for (int m = 0; m < 2; ++m)
#pragma unroll
    for (int n = 0; n < 2; ++n) {
      int col = n0 + wc * 32 + n * 16 + lo;
#pragma unroll
      for (int r = 0; r < 4; ++r) {
        int rowg = m0 + wr * 32 + m * 16 + hi * 4 + r;
        unsigned short v = f2bf(acc[m][n][r]);
        if (z == 0)
          Kb[(size_t)rowg * 512 + col] = v;
        else
          VTb[((size_t)(rowg >> 8) * 512 + col) * 256 + (rowg & 255)] = v;
      }
    }
}

// ---------------------------------------------------------------- attention (unchanged from R2)
__global__ void attn_kernel(const unsigned short* __restrict__ Qb,
                            const unsigned short* __restrict__ Kb,
                            const unsigned short* __restrict__ VTb,
                            const unsigned char* __restrict__ Mu8,
                            unsigned short* __restrict__ AOb) {
  __shared__ unsigned short kt[256 * 64];  // K tile, then P overlay
  const int tid = threadIdx.x, w = tid >> 6, lane = tid & 63;
  const int lo = lane & 15, hi = lane >> 4;
  const int bid = blockIdx.x;
  const int wg = (bid & 7) * 256 + (bid >> 3);
  const int qt = wg & 63, h = (wg >> 6) & 7, b = wg >> 9;

#pragma unroll
  for (int c = 0; c < 8; ++c) {
    int o = (tid + c * 256) * 16;
    int j = o >> 7, colb = (o & 127) ^ ((j & 7) << 4);
    gl_lds16((const char*)Kb + ((size_t)((b * 256 + j) * 512 + h * 64)) * 2 + colb,
             (char*)kt + (w * 64 + c * 256) * 16);
  }
  short8 qf[2];
  {
    int qrow = qt * 64 + w * 16 + lo;
#pragma unroll
    for (int kk = 0; kk < 2; ++kk)
      qf[kk] = *(const short8*)&Qb[(size_t)(b * 4096 + qrow) * 512 + h * 64 + kk * 32 + hi * 8];
  }
  __syncthreads();

  f32x4 acc[16];
#pragma unroll
  for (int nt = 0; nt < 16; ++nt) acc[nt] = (f32x4){0.f, 0.f, 0.f, 0.f};
#pragma unroll
  for (int nt = 0; nt < 16; ++nt) {
    int j = nt * 16 + lo;
#pragma unroll
    for (int kk = 0; kk < 2; ++kk) {
      short8 bfr = *(const short8*)((const char*)kt + j * 128 +
                                    (((kk * 32 + hi * 8) * 2) ^ ((j & 7) << 4)));
      acc[nt] = __builtin_amdgcn_mfma_f32_16x16x32_bf16(qf[kk], bfr, acc[nt], 0, 0, 0);
    }
  }

  const unsigned char* mrow = Mu8 + ((size_t)(h & 3) * 4096 + qt * 64 + w * 16) * 256;
  uint4 mv[4];
#pragma unroll
  for (int r = 0; r < 4; ++r)
    mv[r] = *(const uint4*)(mrow + (hi * 4 + r) * 256 + lo * 16);

  float rmax[4] = {-3e38f, -3e38f, -3e38f, -3e38f};
#pragma unroll
  for (int nt = 0; nt < 16; ++nt)
#pragma unroll
    for (int r = 0; r < 4; ++r) {
      float s = acc[nt][r] * 0.125f;
      acc[nt][r] = s;
      rmax[r] = fmaxf(rmax[r], s);
    }
#pragma unroll
  for (int r = 0; r < 4; ++r) {
#pragma unroll
    for (int m2 = 1; m2 < 16; m2 <<= 1)
      rmax[r] = fmaxf(rmax[r], __shfl_xor(rmax[r], m2, 64));
  }
  float rsum[4] = {0.f, 0.f, 0.f, 0.f};
#pragma unroll
  for (int nt = 0; nt < 16; ++nt)
#pragma unroll
    for (int r = 0; r < 4; ++r) {
      unsigned int word = (nt < 4) ? mv[r].x : (nt < 8) ? mv[r].y : (nt < 12) ? mv[r].z : mv[r].w;
      unsigned int mbyte = (word >> ((nt & 3) * 8)) & 0xFFu;
      float p = __expf(acc[nt][r] - rmax[r]);
      p = mbyte ? p : 0.f;
      acc[nt][r] = p;
      rsum[r] += p;
    }
#pragma unroll
  for (int r = 0; r < 4; ++r) {
#pragma unroll
    for (int m2 = 1; m2 < 16; m2 <<= 1)
      rsum[r] += __shfl_xor(rsum[r], m2, 64);
    rsum[r] = 1.f / rsum[r];
  }

  __syncthreads();  // QK^T LDS reads done -> overlay P on kt

  {
    unsigned short* pl = kt;
#pragma unroll
    for (int r = 0; r < 4; ++r) {
      int q = w * 16 + hi * 4 + r;
      char* prow = (char*)pl + q * 512;
      int q7s = (q & 7) << 4;
#pragma unroll
      for (int nt = 0; nt < 16; ++nt) {
        *(unsigned short*)(prow + (((nt * 16 + lo) * 2) ^ q7s)) = f2bf(acc[nt][r] * rsum[r]);
      }
    }
  }
  __syncthreads();

  const int dh = w & 1, qh = w >> 1;
  f32x4 aco[2][2];
#pragma unroll
  for (int m = 0; m < 2; ++m)
#pragma unroll
    for (int n = 0; n < 2; ++n) aco[m][n] = (f32x4){0.f, 0.f, 0.f, 0.f};
  const size_t vbase = ((size_t)b * 512 + h * 64 + dh * 32) * 256;
#pragma unroll
  for (int ks = 0; ks < 8; ++ks) {
    short8 pa[2];
#pragma unroll
    for (int m = 0; m < 2; ++m) {
      int q = qh * 32 + m * 16 + lo;
      pa[m] = *(const short8*)((const char*)kt + q * 512 +
                               (((ks * 32 + hi * 8) * 2) ^ ((q & 7) << 4)));
    }
#pragma unroll
    for (int n = 0; n < 2; ++n) {
      short8 vb = *(const short8*)&VTb[vbase + (size_t)(n * 16 + lo) * 256 + ks * 32 + hi * 8];
#pragma unroll
      for (int m = 0; m < 2; ++m)
        aco[m][n] = __builtin_amdgcn_mfma_f32_16x16x32_bf16(pa[m], vb, aco[m][n], 0, 0, 0);
    }
  }

#pragma unroll
  for (int m = 0; m < 2; ++m)
#pragma unroll
    for (int n = 0; n < 2; ++n) {
      int col = h * 64 + dh * 32 + n * 16 + lo;
#pragma unroll
      for (int r = 0; r < 4; ++r) {
        int rowg = qt * 64 + qh * 32 + m * 16 + hi * 4 + r;
        AOb[(size_t)(b * 4096 + rowg) * 512 + col] = f2bf(aco[m][n][r]);
      }
    }
}

// ----------------------------------------------------------------
extern "C" void kernel_launch(void* const* d_in, const int* in_sizes, int n_in,
                              void* d_out, int out_size, void* d_ws, size_t ws_size,
                              hipStream_t stream) {
  const float* x = (const float*)d_in[0];     // (4,4096,512)
  const float* ctx = (const float*)d_in[1];   // (4,256,768)
  const int* mask = (const int*)d_in[2];      // (4,256,128,128)
  const float* Wq = (const float*)d_in[3];    // (512,512)
  const float* Wk = (const float*)d_in[4];    // (768,512)
  const float* Wv = (const float*)d_in[5];    // (768,512)
  const float* Wo = (const float*)d_in[6];    // (512,512)
  const float* bo = (const float*)d_in[7];    // (512,)
  float* out = (float*)d_out;                 // (4,4096,512) f32

  char* ws = (char*)d_ws;
  size_t off = 0;
  auto alloc = [&](size_t bytes) {
    char* p = ws + off;
    off += (bytes + 255) & ~(size_t)255;
    return p;
  };
  unsigned short* xb   = (unsigned short*)alloc((size_t)16384 * 512 * 2);
  unsigned short* ctxb = (unsigned short*)alloc((size_t)1024 * 768 * 2);
  unsigned short* WqT  = (unsigned short*)alloc((size_t)512 * 512 * 2);
  unsigned short* WkT  = (unsigned short*)alloc((size_t)512 * 768 * 2);
  unsigned short* WvT  = (unsigned short*)alloc((size_t)512 * 768 * 2);
  unsigned short* WoT  = (unsigned short*)alloc((size_t)512 * 512 * 2);
  unsigned short* Qb   = (unsigned short*)alloc((size_t)16384 * 512 * 2);
  unsigned short* Kb   = (unsigned short*)alloc((size_t)1024 * 512 * 2);
  unsigned short* VTb  = (unsigned short*)alloc((size_t)4 * 512 * 256 * 2);
  unsigned short* AOb  = (unsigned short*)alloc((size_t)16384 * 512 * 2);
  unsigned char*  Mu8  = (unsigned char*)alloc((size_t)4 * 4096 * 256);

  cvt_both<<<8960, 256, 0, stream>>>(x, ctx, xb, ctxb);
  transW_all<<<320, 256, 0, stream>>>(Wq, Wk, Wv, Wo, WqT, WkT, WvT, WoT);
  maskprep<<<dim3(64, 4), 256, 0, stream>>>(mask, Mu8);

  gemm_kv64<<<dim3(16, 8, 2), 256, 0, stream>>>(ctxb, WkT, WvT, Kb, VTb);
  gemm128<0><<<dim3(128, 4), 256, 0, stream>>>(xb, WqT, Qb, nullptr, 16384, 512, 512);

  attn_kernel<<<2048, 256, 0, stream>>>(Qb, Kb, VTb, Mu8, AOb);

  gemm128<2><<<dim3(128, 4), 256, 0, stream>>>(AOb, WoT, out, bo, 16384, 512, 512);
}